// Round 2
// baseline (581.660 us; speedup 1.0000x reference)
//
#include <hip/hip_runtime.h>
#include <math.h>

// CapsuleLayer routing on MI355X (gfx950). All fp32 (per reference dtypes).
// B=64, n_nodes=2048, n_caps=32, in_C=16, out_C=32, 3 routing iterations.
// priors = [64,2048,32,32] fp32 = 512 MB -> never materialized; three
// recompute passes over W with reduce+squash between them:
//   P0: s0 = (1/32) * sum_n priors                       -> partial[nb][b][k][o]
//   R0: reduce partials over nb + squash -> outv
//   P1: delta0 = priors.out0; logits=delta0; probs=softmax_k(delta0);
//       s1 = sum_n probs*priors                          -> partial
//   R1: reduce+squash -> outv
//   P2: delta1 = priors.out1; probs=softmax_k(logits+delta1); s2 -> partial
//   R2: reduce+squash -> d_out (fp32)
// Pass kernel: block=512 thr covers 32 b x 32 k x 32 o, loops 8 nodes; W[n]
// (64 KB fp32) staged in LDS (k-stride padded 512->516 floats vs bank
// conflicts); per-thread tile = 2 b (same k) x 32 o fp32 accumulators.

#define BATCH   64
#define NNODES  2048
#define NCAPS   32
#define INC     16
#define OUTC    32
#define BB      32                 // batches per block
#define NCHUNK  8                  // nodes per block
#define NBLK    (NNODES / NCHUNK)  // 256 node-chunks
#define THREADS 512
#define WK_STRIDE 516              // fp32 floats per k-slice in LDS (512 + 4 pad)

template <int PASS>
__global__ __launch_bounds__(THREADS, 1) void pass_kernel(
    const float* __restrict__ xg,   // fp32 [B, NNODES, INC]
    const float* __restrict__ Wg,   // fp32 [NNODES, NCAPS, INC, OUTC]
    const float* __restrict__ outv, // fp32 [B, NCAPS, OUTC] (PASS>=1)
    float* __restrict__ logits,     // fp32 [B, NNODES, NCAPS]
    float* __restrict__ partial)    // fp32 [NBLK, B, NCAPS, OUTC]
{
    __shared__ float w_lds[NCAPS * WK_STRIDE];      // 66048 B
    __shared__ float x_lds[BB][INC + 1];            //  2176 B
    __shared__ float delta_lds[BB][NCAPS + 1];      //  4224 B

    const int t   = threadIdx.x;
    const int nb  = blockIdx.x;          // node-chunk
    const int bg  = blockIdx.y;          // batch group (0..1)
    const int b0  = bg * BB;
    const int k   = t >> 4;              // 0..31 (capsule)
    const int bq  = t & 15;
    const int bl0 = bq * 2;
    const int bl1 = bq * 2 + 1;

    float acc0[OUTC], acc1[OUTC];
#pragma unroll
    for (int o = 0; o < OUTC; ++o) { acc0[o] = 0.f; acc1[o] = 0.f; }

    float outr0[OUTC], outr1[OUTC];
    if constexpr (PASS >= 1) {
        const float4* o0 = (const float4*)&outv[((b0 + bl0) * NCAPS + k) * OUTC];
        const float4* o1 = (const float4*)&outv[((b0 + bl1) * NCAPS + k) * OUTC];
#pragma unroll
        for (int q = 0; q < OUTC / 4; ++q) {
            float4 a = o0[q]; float4 b = o1[q];
            outr0[4*q+0]=a.x; outr0[4*q+1]=a.y; outr0[4*q+2]=a.z; outr0[4*q+3]=a.w;
            outr1[4*q+0]=b.x; outr1[4*q+1]=b.y; outr1[4*q+2]=b.z; outr1[4*q+3]=b.w;
        }
    }

    for (int j = 0; j < NCHUNK; ++j) {
        const int n = nb * NCHUNK + j;
        __syncthreads();   // protect LDS from previous iteration's readers
        // ---- stage W[n]: 16384 fp32 -> LDS (16B loads, 16B LDS stores) ----
        {
            const float4* src = (const float4*)(Wg + (size_t)n * (NCAPS * INC * OUTC));
#pragma unroll
            for (int r = 0; r < (NCAPS * INC * OUTC / 4) / THREADS; ++r) {  // 8 iters
                int idx4 = t + r * THREADS;
                float4 v = src[idx4];
                int e   = idx4 * 4;
                int kk  = e >> 9;        // /512
                int rem = e & 511;
                *(float4*)&w_lds[kk * WK_STRIDE + rem] = v;   // both 16B-aligned
            }
        }
        // ---- stage x rows: 32 b x 16 i ----
        {
            int bl = t >> 4;
            int i  = t & 15;
            x_lds[bl][i] = xg[((size_t)(b0 + bl) * NNODES + n) * INC + i];
        }
        __syncthreads();

        if constexpr (PASS == 0) {
            // uniform probs: accumulate priors; scale by 1/32 at the end
#pragma unroll
            for (int i = 0; i < INC; ++i) {
                float xa = x_lds[bl0][i];
                float xb = x_lds[bl1][i];
                const float* wrow = &w_lds[k * WK_STRIDE + i * OUTC];
#pragma unroll
                for (int o = 0; o < OUTC; ++o) {
                    float w = wrow[o];
                    acc0[o] = fmaf(xa, w, acc0[o]);
                    acc1[o] = fmaf(xb, w, acc1[o]);
                }
            }
        } else {
            float pr0[OUTC], pr1[OUTC];
#pragma unroll
            for (int o = 0; o < OUTC; ++o) { pr0[o] = 0.f; pr1[o] = 0.f; }
#pragma unroll
            for (int i = 0; i < INC; ++i) {
                float xa = x_lds[bl0][i];
                float xb = x_lds[bl1][i];
                const float* wrow = &w_lds[k * WK_STRIDE + i * OUTC];
#pragma unroll
                for (int o = 0; o < OUTC; ++o) {
                    float w = wrow[o];
                    pr0[o] = fmaf(xa, w, pr0[o]);
                    pr1[o] = fmaf(xb, w, pr1[o]);
                }
            }
            // delta = prior . out
            float d0 = 0.f, d1 = 0.f;
#pragma unroll
            for (int o = 0; o < OUTC; ++o) {
                d0 = fmaf(pr0[o], outr0[o], d0);
                d1 = fmaf(pr1[o], outr1[o], d1);
            }
            float l0 = d0, l1 = d1;
            const size_t li0 = ((size_t)(b0 + bl0) * NNODES + n) * NCAPS + k;
            const size_t li1 = ((size_t)(b0 + bl1) * NNODES + n) * NCAPS + k;
            if constexpr (PASS == 2) {
                l0 += logits[li0];
                l1 += logits[li1];
            } else {
                logits[li0] = d0;
                logits[li1] = d1;
            }
            delta_lds[bl0][k] = l0;
            delta_lds[bl1][k] = l1;
            __syncthreads();
            // softmax over k (each thread recomputes for its two b rows)
            float m0 = -1e30f, m1 = -1e30f;
#pragma unroll
            for (int kk = 0; kk < NCAPS; ++kk) {
                m0 = fmaxf(m0, delta_lds[bl0][kk]);
                m1 = fmaxf(m1, delta_lds[bl1][kk]);
            }
            float s0 = 0.f, s1 = 0.f;
#pragma unroll
            for (int kk = 0; kk < NCAPS; ++kk) {
                s0 += __expf(delta_lds[bl0][kk] - m0);
                s1 += __expf(delta_lds[bl1][kk] - m1);
            }
            float p0 = __expf(l0 - m0) / s0;
            float p1 = __expf(l1 - m1) / s1;
#pragma unroll
            for (int o = 0; o < OUTC; ++o) {
                acc0[o] = fmaf(p0, pr0[o], acc0[o]);
                acc1[o] = fmaf(p1, pr1[o], acc1[o]);
            }
        }
    }

    const float scale = (PASS == 0) ? (1.f / NCAPS) : 1.f;
    float4* p0 = (float4*)&partial[(((size_t)nb * BATCH + (b0 + bl0)) * NCAPS + k) * OUTC];
    float4* p1 = (float4*)&partial[(((size_t)nb * BATCH + (b0 + bl1)) * NCAPS + k) * OUTC];
#pragma unroll
    for (int q = 0; q < OUTC / 4; ++q) {
        float4 v0, v1;
        v0.x = acc0[4*q+0] * scale; v0.y = acc0[4*q+1] * scale;
        v0.z = acc0[4*q+2] * scale; v0.w = acc0[4*q+3] * scale;
        v1.x = acc1[4*q+0] * scale; v1.y = acc1[4*q+1] * scale;
        v1.z = acc1[4*q+2] * scale; v1.w = acc1[4*q+3] * scale;
        p0[q] = v0;
        p1[q] = v1;
    }
}

// Reduce partials over node-chunks, then squash within each (b,k) 32-vector.
// tid = b*1024 + k*32 + o; the 32 lanes of a (b,k) group are contiguous, so a
// shuffle-xor butterfly over masks 1..16 sums ||v||^2 within the group.
__global__ __launch_bounds__(256) void reduce_squash(
    const float* __restrict__ partial,
    float* __restrict__ outf)
{
    const int tid = blockIdx.x * 256 + threadIdx.x;   // 0..65535
    float v = 0.f;
    for (int nb = 0; nb < NBLK; ++nb)
        v += partial[(size_t)nb * (BATCH * NCAPS * OUTC) + tid];
    float sq = v * v;
#pragma unroll
    for (int off = 1; off < 32; off <<= 1)
        sq += __shfl_xor(sq, off);
    // squash: (sq/(1+sq)) * v/sqrt(sq)
    float coef = sq / ((1.f + sq) * sqrtf(sq));
    outf[tid] = v * coef;
}

extern "C" void kernel_launch(void* const* d_in, const int* in_sizes, int n_in,
                              void* d_out, int out_size, void* d_ws, size_t ws_size,
                              hipStream_t stream)
{
    const float* xg = (const float*)d_in[0];   // fp32 x
    const float* Wg = (const float*)d_in[1];   // fp32 route_weights
    float* outp = (float*)d_out;               // fp32 output [64,1,32,32]

    char* ws = (char*)d_ws;
    float* partial = (float*)ws;                                          // 64 MiB
    float* logits  = (float*)(ws + (size_t)NBLK * BATCH * NCAPS * OUTC * sizeof(float));   // 16 MiB
    float* outv    = (float*)(ws + (size_t)NBLK * BATCH * NCAPS * OUTC * sizeof(float)
                                 + (size_t)BATCH * NNODES * NCAPS * sizeof(float));        // 256 KiB

    dim3 grid(NBLK, BATCH / BB);   // (256, 2)
    const int rblocks = BATCH * NCAPS * OUTC / 256;  // 256

    // iter 0
    pass_kernel<0><<<grid, THREADS, 0, stream>>>(xg, Wg, nullptr, logits, partial);
    reduce_squash<<<rblocks, 256, 0, stream>>>(partial, outv);
    // iter 1
    pass_kernel<1><<<grid, THREADS, 0, stream>>>(xg, Wg, outv, logits, partial);
    reduce_squash<<<rblocks, 256, 0, stream>>>(partial, outv);
    // iter 2
    pass_kernel<2><<<grid, THREADS, 0, stream>>>(xg, Wg, outv, logits, partial);
    reduce_squash<<<rblocks, 256, 0, stream>>>(partial, outp);
}